// Round 4
// baseline (407.010 us; speedup 1.0000x reference)
//
#include <hip/hip_runtime.h>
#include <math.h>

#define Bb 8
#define Tt 1024
#define Dd 512
#define Hh 8
#define HSs 64

typedef __attribute__((ext_vector_type(8))) short bf16x8;
typedef __attribute__((ext_vector_type(4))) float f32x4;
typedef __attribute__((ext_vector_type(8))) unsigned short u16x8;

__device__ __forceinline__ unsigned short f2bf(float f) {
  unsigned u = __float_as_uint(f);
  u += 0x7fffu + ((u >> 16) & 1u);
  return (unsigned short)(u >> 16);
}
__device__ __forceinline__ float bf2f(unsigned short s) {
  return __uint_as_float(((unsigned)s) << 16);
}
__device__ __forceinline__ void gload16(const void* g, void* l) {
  __builtin_amdgcn_global_load_lds(
      (const __attribute__((address_space(1))) void*)g,
      (__attribute__((address_space(3))) void*)l, 16, 0, 0);
}

// ---------------- prep: weights -> bf16, transposed, via LDS 64x64 tiles ----
// blocks 0..255: z<4 (wq,wk,wv,wpos (h,d,o)) -> wt[z][h*64+o][d]
// blocks 256..319: wo (h,o,d) -> wo_t[d][h*64+o]
__global__ __launch_bounds__(256) void prep_w(
    const float* __restrict__ wq, const float* __restrict__ wk,
    const float* __restrict__ wv, const float* __restrict__ wpos,
    const float* __restrict__ wo, unsigned short* __restrict__ wt,
    unsigned short* __restrict__ wo_t) {
  __shared__ unsigned short lds[64][65];
  int t = threadIdx.x, blk = blockIdx.x;
  if (blk < 256) {
    int z = blk >> 6, h = (blk >> 3) & 7, dt = blk & 7;
    const float* src = (z == 0) ? wq : (z == 1) ? wk : (z == 2) ? wv : wpos;
    const float* base = src + (size_t)h * 32768 + (size_t)dt * 4096;  // contiguous 64x64
#pragma unroll
    for (int p = 0; p < 4; ++p) {
      int idx = p * 1024 + t * 4;      // d = idx>>6, o = idx&63
      float4 v = *(const float4*)(base + idx);
      int d = idx >> 6, o = idx & 63;
      lds[o + 0][d] = f2bf(v.x);
      lds[o + 1][d] = f2bf(v.y);
      lds[o + 2][d] = f2bf(v.z);
      lds[o + 3][d] = f2bf(v.w);
    }
    __syncthreads();
    int o = t >> 2, dc = (t & 3) * 16;
    u16x8 w0, w1;
#pragma unroll
    for (int j = 0; j < 8; ++j) { w0[j] = lds[o][dc + j]; w1[j] = lds[o][dc + 8 + j]; }
    unsigned short* dst =
        wt + (size_t)z * 262144 + (size_t)((h << 6) + o) * 512 + dt * 64 + dc;
    *(u16x8*)dst = w0;
    *(u16x8*)(dst + 8) = w1;
  } else {
    int b2 = blk - 256, h = b2 >> 3, dt = b2 & 7;
    const float* base = wo + (size_t)h * 32768 + (size_t)dt * 64;  // rows o stride 512
#pragma unroll
    for (int p = 0; p < 4; ++p) {
      int idx = p * 1024 + t * 4;      // o = idx>>6, dl = idx&63
      int o = idx >> 6, dl = idx & 63;
      float4 v = *(const float4*)(base + (size_t)o * 512 + dl);
      lds[dl + 0][o] = f2bf(v.x);
      lds[dl + 1][o] = f2bf(v.y);
      lds[dl + 2][o] = f2bf(v.z);
      lds[dl + 3][o] = f2bf(v.w);
    }
    __syncthreads();
    int dl = t >> 2, oc = (t & 3) * 16;
    u16x8 w0, w1;
#pragma unroll
    for (int j = 0; j < 8; ++j) { w0[j] = lds[dl][oc + j]; w1[j] = lds[dl][oc + 8 + j]; }
    unsigned short* dst = wo_t + (size_t)(dt * 64 + dl) * 512 + (h << 6) + oc;
    *(u16x8*)dst = w0;
    *(u16x8*)(dst + 8) = w1;
  }
}

// ------------- LayerNorm (blocks 0..2047) + pos->bf16 (2048..4095) -------------
__global__ __launch_bounds__(256) void ln_pos_kernel(
    const float* __restrict__ x, const float* __restrict__ pos,
    const float* __restrict__ gamma, const float* __restrict__ beta,
    unsigned short* __restrict__ y, unsigned short* __restrict__ posb) {
  int wid = threadIdx.x >> 6, lane = threadIdx.x & 63;
  int blk = blockIdx.x;
  if (blk >= 2048) {
    int row = (blk - 2048) * 4 + wid;
    const float* pr = pos + (size_t)row * Dd + lane * 8;
    float4 a = *(const float4*)pr;
    float4 b = *(const float4*)(pr + 4);
    float v[8] = {a.x, a.y, a.z, a.w, b.x, b.y, b.z, b.w};
    u16x8 o8;
#pragma unroll
    for (int j = 0; j < 8; ++j) o8[j] = f2bf(v[j]);
    *(u16x8*)(posb + (size_t)row * Dd + lane * 8) = o8;
    return;
  }
  int row = blk * 4 + wid;
  const float* xr = x + (size_t)row * Dd + lane * 8;
  float4 v0 = *(const float4*)xr;
  float4 v1 = *(const float4*)(xr + 4);
  float xv[8] = {v0.x, v0.y, v0.z, v0.w, v1.x, v1.y, v1.z, v1.w};
  float s = 0.f, ss = 0.f;
#pragma unroll
  for (int j = 0; j < 8; ++j) { s += xv[j]; ss += xv[j] * xv[j]; }
#pragma unroll
  for (int m = 1; m < 64; m <<= 1) {
    s += __shfl_xor(s, m);
    ss += __shfl_xor(ss, m);
  }
  float mu = s * (1.f / 512.f);
  float var = ss * (1.f / 512.f) - mu * mu;
  float inv = rsqrtf(var + 1e-3f);
  const float4 g0 = *(const float4*)(gamma + lane * 8);
  const float4 g1 = *(const float4*)(gamma + lane * 8 + 4);
  const float4 b0 = *(const float4*)(beta + lane * 8);
  const float4 b1 = *(const float4*)(beta + lane * 8 + 4);
  float gv[8] = {g0.x, g0.y, g0.z, g0.w, g1.x, g1.y, g1.z, g1.w};
  float bv[8] = {b0.x, b0.y, b0.z, b0.w, b1.x, b1.y, b1.z, b1.w};
  u16x8 o8;
#pragma unroll
  for (int j = 0; j < 8; ++j)
    o8[j] = f2bf((xv[j] - mu) * inv * gv[j] + bv[j]);
  *(u16x8*)(y + (size_t)row * Dd + lane * 8) = o8;
}

// ------- projection GEMM: [8192,512] x B^T[512,512] -> q/k/v/p [B,H,T,64] -------
// Double-buffered [64][32] tiles via global_load_lds; chunk swizzle
// chunk ^= (row>>1)&3 on both write-source and read (2-way banks, free).
__global__ __launch_bounds__(256) void proj_gemm(
    const unsigned short* __restrict__ y, const unsigned short* __restrict__ posb,
    const unsigned short* __restrict__ wt, unsigned short* __restrict__ q,
    unsigned short* __restrict__ k, unsigned short* __restrict__ v,
    unsigned short* __restrict__ p) {
  __shared__ __align__(16) unsigned short la[2][64 * 32];
  __shared__ __align__(16) unsigned short lb[2][64 * 32];
  int z = blockIdx.z, h = blockIdx.y, m0 = blockIdx.x * 64;
  const unsigned short* A = (z < 3) ? y : posb;
  const unsigned short* Bt = wt + (size_t)z * 262144 + (size_t)h * 64 * 512;
  unsigned short* dst = (z == 0) ? q : (z == 1) ? k : (z == 2) ? v : p;
  int tid = threadIdx.x, wid = tid >> 6, lane = tid & 63;
  int g = lane >> 4, cl = lane & 15;
  int srow = (wid << 4) + (lane >> 2);                    // 0..63
  int scsw = (((lane & 3) ^ ((lane >> 3) & 3)) << 3);     // swizzled src chunk
  const unsigned short* asrc = A + (size_t)(m0 + srow) * 512 + scsw;
  const unsigned short* bsrc = Bt + (size_t)srow * 512 + scsw;
  int rk = (cl >> 1) & 3;                                 // read swizzle key
  int aoff = (16 * wid + cl) * 32 + ((g ^ rk) << 3);
  f32x4 acc[4] = {};
  gload16(asrc, la[0] + (wid << 9));
  gload16(bsrc, lb[0] + (wid << 9));
  __syncthreads();
  for (int ks = 0; ks < 16; ++ks) {
    int cur = ks & 1;
    if (ks < 15) {
      gload16(asrc + (ks + 1) * 32, la[cur ^ 1] + (wid << 9));
      gload16(bsrc + (ks + 1) * 32, lb[cur ^ 1] + (wid << 9));
    }
    bf16x8 af = *(const bf16x8*)&la[cur][aoff];
#pragma unroll
    for (int nt = 0; nt < 4; ++nt) {
      bf16x8 bf = *(const bf16x8*)&lb[cur][(nt * 16 + cl) * 32 + ((g ^ rk) << 3)];
      acc[nt] = __builtin_amdgcn_mfma_f32_16x16x32_bf16(af, bf, acc[nt], 0, 0, 0);
    }
    __syncthreads();
  }
#pragma unroll
  for (int nt = 0; nt < 4; ++nt)
#pragma unroll
    for (int r = 0; r < 4; ++r) {
      int m = m0 + 16 * wid + g * 4 + r;
      int b = m >> 10, t = m & 1023;
      int o = nt * 16 + cl;
      dst[(((size_t)(b * 8 + h)) * 1024 + t) * 64 + o] = f2bf(acc[nt][r]);
    }
}

// ------- bd_raw = (q + pos_bias_v) . P^T per (b,h) chunk: [T,T] bf16 -------
__global__ __launch_bounds__(256) void bd_gemm(
    const unsigned short* __restrict__ q, const unsigned short* __restrict__ p,
    const float* __restrict__ vbias, unsigned short* __restrict__ bdraw, int bh0) {
  __shared__ __align__(16) unsigned short pl[64 * 64];
  int px = blockIdx.x, bh = bh0 + px, b = bh >> 3, h = bh & 7;
  int r0 = blockIdx.y * 64, c0 = blockIdx.z * 64;
  int tid = threadIdx.x, wid = tid >> 6, lane = tid & 63;
  int g = lane >> 4, cl = lane & 15;
  const unsigned short* qbase =
      q + (((size_t)(b * 8 + h)) * 1024 + r0 + 16 * wid + cl) * 64;
  bf16x8 aq[2];
#pragma unroll
  for (int ks = 0; ks < 2; ++ks) {
    bf16x8 raw = *(const bf16x8*)&qbase[ks * 32 + g * 8];
#pragma unroll
    for (int j = 0; j < 8; ++j) {
      float f = bf2f((unsigned short)raw[j]) + vbias[h * 64 + ks * 32 + g * 8 + j];
      raw[j] = (short)f2bf(f);
    }
    aq[ks] = raw;
  }
  // stage P tile via global_load_lds, pre-swizzled source chunk
  const unsigned short* pbase = p + (((size_t)(b * 8 + h)) * 1024 + c0) * 64;
  {
    int rlo = lane >> 3;                       // 0..7
    int scc = ((lane & 7) ^ rlo) << 3;         // source element chunk*8
#pragma unroll
    for (int it = 0; it < 2; ++it) {
      int seg = wid + it * 4;                  // rows 8seg..8seg+7
      gload16(pbase + (size_t)(seg * 8 + rlo) * 64 + scc,
              (char*)pl + (seg << 10));
    }
  }
  __syncthreads();
  f32x4 acc[4] = {};
#pragma unroll
  for (int ks = 0; ks < 2; ++ks)
#pragma unroll
    for (int nt = 0; nt < 4; ++nt) {
      int row = nt * 16 + cl;
      int byte = row * 128 + ((ks * 64 + g * 16) ^ ((row & 7) << 4));
      bf16x8 bf = *(const bf16x8*)((char*)pl + byte);
      acc[nt] = __builtin_amdgcn_mfma_f32_16x16x32_bf16(aq[ks], bf, acc[nt], 0, 0, 0);
    }
  unsigned short* out =
      bdraw + (size_t)px * 1048576 + (size_t)(r0 + 16 * wid) * 1024 + c0;
#pragma unroll
  for (int nt = 0; nt < 4; ++nt)
#pragma unroll
    for (int r = 0; r < 4; ++r)
      out[(size_t)(g * 4 + r) * 1024 + nt * 16 + cl] = f2bf(acc[nt][r]);
}

// ---------------- fused flash attention with rel-shift bd ----------------
// V staged per-thread as one 16B key-chunk (o = lane, kc per wave) ->
// single b128 LDS store, 2-way banks (replaces 16-way scalar scatter).
__global__ __launch_bounds__(256) void attn_kernel(
    const unsigned short* __restrict__ q, const unsigned short* __restrict__ kg,
    const unsigned short* __restrict__ vg, const float* __restrict__ ubias,
    const unsigned short* __restrict__ bdraw, unsigned short* __restrict__ ctx,
    int bh0) {
  __shared__ __align__(16) unsigned short kt[2][64 * 64];
  __shared__ __align__(16) unsigned short vt[2][64 * 64];
  __shared__ __align__(16) unsigned short pl[4][16 * 64];
  int px = blockIdx.x, bh = bh0 + px, b = bh >> 3, h = bh & 7;
  int i0 = blockIdx.y * 64;
  int tid = threadIdx.x, wid = tid >> 6, lane = tid & 63;
  int g = lane >> 4, cl = lane & 15;
  size_t bhoff = ((size_t)(b * 8 + h)) * 1024;
  const unsigned short* qbase = q + (bhoff + i0 + 16 * wid + cl) * 64;
  bf16x8 aq[2];
#pragma unroll
  for (int ks = 0; ks < 2; ++ks) {
    bf16x8 raw = *(const bf16x8*)&qbase[ks * 32 + g * 8];
#pragma unroll
    for (int j = 0; j < 8; ++j) {
      float f = bf2f((unsigned short)raw[j]) + ubias[h * 64 + ks * 32 + g * 8 + j];
      raw[j] = (short)f2bf(f);
    }
    aq[ks] = raw;
  }
  f32x4 oacc[4] = {};
  float mrun[4], lrun[4];
#pragma unroll
  for (int r = 0; r < 4; ++r) { mrun[r] = -INFINITY; lrun[r] = 0.f; }
  const unsigned short* bdb = bdraw + (size_t)px * 1048576;
  const unsigned short* kbase = kg + bhoff * 64;
  const unsigned short* vbase = vg + bhoff * 64;
  int rlo = lane >> 3;                       // K-staging source row-in-8
  int scc = ((lane & 7) ^ rlo) << 3;         // pre-swizzled source chunk
  // V staging mapping: o = lane, key chunks kc0 = wid, kc1 = wid+4
  int kc0 = wid, kc1 = wid + 4;
  int vby0 = lane * 128 + ((kc0 * 16) ^ ((lane & 7) << 4));
  int vby1 = lane * 128 + ((kc1 * 16) ^ ((lane & 7) << 4));

  // prologue: stage tile 0
#pragma unroll
  for (int it = 0; it < 2; ++it) {
    int seg = wid + it * 4;
    gload16(kbase + (size_t)(seg * 8 + rlo) * 64 + scc, (char*)kt[0] + (seg << 10));
  }
  {
    u16x8 va, vb;
#pragma unroll
    for (int j = 0; j < 8; ++j) {
      va[j] = vbase[(size_t)(kc0 * 8 + j) * 64 + lane];
      vb[j] = vbase[(size_t)(kc1 * 8 + j) * 64 + lane];
    }
    *(u16x8*)((char*)vt[0] + vby0) = va;
    *(u16x8*)((char*)vt[0] + vby1) = vb;
  }
  __syncthreads();

  for (int jt = 0; jt < 16; ++jt) {
    int cur = jt & 1;
    unsigned short* ktc = kt[cur];
    unsigned short* vtc = vt[cur];
    u16x8 nva, nvb;
    if (jt < 15) {
      int j1 = (jt + 1) * 64;
#pragma unroll
      for (int it = 0; it < 2; ++it) {
        int seg = wid + it * 4;
        gload16(kbase + (size_t)(j1 + seg * 8 + rlo) * 64 + scc,
                (char*)kt[cur ^ 1] + (seg << 10));
      }
#pragma unroll
      for (int j = 0; j < 8; ++j) {
        nva[j] = vbase[(size_t)(j1 + kc0 * 8 + j) * 64 + lane];
        nvb[j] = vbase[(size_t)(j1 + kc1 * 8 + j) * 64 + lane];
      }
    }
    int j0 = jt * 64;
    // S = Qu . K^T
    f32x4 sacc[4] = {};
#pragma unroll
    for (int ks = 0; ks < 2; ++ks)
#pragma unroll
      for (int nt = 0; nt < 4; ++nt) {
        int row = nt * 16 + cl;
        bf16x8 bk = *(const bf16x8*)((char*)ktc + row * 128 +
                                     ((ks * 64 + g * 16) ^ ((row & 7) << 4)));
        sacc[nt] = __builtin_amdgcn_mfma_f32_16x16x32_bf16(aq[ks], bk, sacc[nt], 0, 0, 0);
      }
    // add rel-shifted bd (bf16), scale
    float pmax[4];
#pragma unroll
    for (int r = 0; r < 4; ++r) pmax[r] = -INFINITY;
#pragma unroll
    for (int nt = 0; nt < 4; ++nt)
#pragma unroll
      for (int r = 0; r < 4; ++r) {
        int i = i0 + 16 * wid + g * 4 + r;
        int j = j0 + nt * 16 + cl;
        float bdv;
        if (j <= i)
          bdv = bf2f(bdb[(size_t)i * 1024 + (j - i + 1023)]);
        else if (j == i + 1)
          bdv = 0.f;
        else
          bdv = bf2f(bdb[(size_t)(i + 1) * 1024 + (j - i - 2)]);
        float s = (sacc[nt][r] + bdv) * 0.125f;
        sacc[nt][r] = s;
        pmax[r] = fmaxf(pmax[r], s);
      }
#pragma unroll
    for (int r = 0; r < 4; ++r) {
      pmax[r] = fmaxf(pmax[r], __shfl_xor(pmax[r], 1));
      pmax[r] = fmaxf(pmax[r], __shfl_xor(pmax[r], 2));
      pmax[r] = fmaxf(pmax[r], __shfl_xor(pmax[r], 4));
      pmax[r] = fmaxf(pmax[r], __shfl_xor(pmax[r], 8));
    }
    float scl[4], rsum[4];
#pragma unroll
    for (int r = 0; r < 4; ++r) {
      float mn = fmaxf(mrun[r], pmax[r]);
      scl[r] = __expf(mrun[r] - mn);
      mrun[r] = mn;
      rsum[r] = 0.f;
    }
#pragma unroll
    for (int nt = 0; nt < 4; ++nt)
#pragma unroll
      for (int r = 0; r < 4; ++r) {
        float pv = __expf(sacc[nt][r] - mrun[r]);
        sacc[nt][r] = pv;
        rsum[r] += pv;
      }
#pragma unroll
    for (int r = 0; r < 4; ++r) {
      rsum[r] += __shfl_xor(rsum[r], 1);
      rsum[r] += __shfl_xor(rsum[r], 2);
      rsum[r] += __shfl_xor(rsum[r], 4);
      rsum[r] += __shfl_xor(rsum[r], 8);
      lrun[r] = lrun[r] * scl[r] + rsum[r];
    }
#pragma unroll
    for (int ot = 0; ot < 4; ++ot) {
      f32x4 t = oacc[ot];
#pragma unroll
      for (int r = 0; r < 4; ++r) t[r] *= scl[r];
      oacc[ot] = t;
    }
    // P -> LDS (wave-private), swizzled
    unsigned short* pw = &pl[wid][0];
#pragma unroll
    for (int nt = 0; nt < 4; ++nt)
#pragma unroll
      for (int r = 0; r < 4; ++r) {
        int row = g * 4 + r, col = nt * 16 + cl;
        *(unsigned short*)((char*)pw + row * 128 +
                           ((col * 2) ^ ((row & 7) << 4))) = f2bf(sacc[nt][r]);
      }
    bf16x8 ap[2];
#pragma unroll
    for (int ks = 0; ks < 2; ++ks)
      ap[ks] = *(const bf16x8*)((char*)pw + cl * 128 +
                                ((ks * 64 + g * 16) ^ ((cl & 7) << 4)));
    // O += P . V
#pragma unroll
    for (int ks = 0; ks < 2; ++ks)
#pragma unroll
      for (int ot = 0; ot < 4; ++ot) {
        int o = ot * 16 + cl;
        bf16x8 bv = *(const bf16x8*)((char*)vtc + o * 128 +
                                     ((ks * 64 + g * 16) ^ ((o & 7) << 4)));
        oacc[ot] = __builtin_amdgcn_mfma_f32_16x16x32_bf16(ap[ks], bv, oacc[ot], 0, 0, 0);
      }
    // late V write for next tile (loads issued at top have drained by now)
    if (jt < 15) {
      unsigned short* vtn = vt[cur ^ 1];
      *(u16x8*)((char*)vtn + vby0) = nva;
      *(u16x8*)((char*)vtn + vby1) = nvb;
    }
    __syncthreads();
  }
#pragma unroll
  for (int ot = 0; ot < 4; ++ot)
#pragma unroll
    for (int r = 0; r < 4; ++r) {
      int i = i0 + 16 * wid + g * 4 + r;
      int c = h * 64 + ot * 16 + cl;
      ctx[((size_t)b * 1024 + i) * 512 + c] = f2bf(oacc[ot][r] / lrun[r]);
    }
}

// ---------------- output GEMM + bias + residual ----------------
__global__ __launch_bounds__(256) void out_gemm(
    const unsigned short* __restrict__ ctx, const unsigned short* __restrict__ wot,
    const float* __restrict__ x, const float* __restrict__ bo,
    float* __restrict__ out) {
  __shared__ __align__(16) unsigned short la[2][64 * 32];
  __shared__ __align__(16) unsigned short lb[2][64 * 32];
  int n0 = blockIdx.y * 64, m0 = blockIdx.x * 64;
  int tid = threadIdx.x, wid = tid >> 6, lane = tid & 63;
  int g = lane >> 4, cl = lane & 15;
  int srow = (wid << 4) + (lane >> 2);
  int scsw = (((lane & 3) ^ ((lane >> 3) & 3)) << 3);
  const unsigned short* asrc = ctx + (size_t)(m0 + srow) * 512 + scsw;
  const unsigned short* bsrc = wot + (size_t)(n0 + srow) * 512 + scsw;
  int rk = (cl >> 1) & 3;
  int aoff = (16 * wid + cl) * 32 + ((g ^ rk) << 3);
  f32x4 acc[4] = {};
  gload16(asrc, la[0] + (wid << 9));
  gload16(bsrc, lb[0] + (wid << 9));
  __syncthreads();
  for (int ks = 0; ks < 16; ++ks) {
    int cur = ks & 1;
    if (ks < 15) {
      gload16(asrc + (ks + 1) * 32, la[cur ^ 1] + (wid << 9));
      gload16(bsrc + (ks + 1) * 32, lb[cur ^ 1] + (wid << 9));
    }
    bf16x8 af = *(const bf16x8*)&la[cur][aoff];
#pragma unroll
    for (int nt = 0; nt < 4; ++nt) {
      bf16x8 bf = *(const bf16x8*)&lb[cur][(nt * 16 + cl) * 32 + ((g ^ rk) << 3)];
      acc[nt] = __builtin_amdgcn_mfma_f32_16x16x32_bf16(af, bf, acc[nt], 0, 0, 0);
    }
    __syncthreads();
  }
#pragma unroll
  for (int nt = 0; nt < 4; ++nt)
#pragma unroll
    for (int r = 0; r < 4; ++r) {
      int m = m0 + 16 * wid + g * 4 + r;
      int n = n0 + nt * 16 + cl;
      out[(size_t)m * 512 + n] = acc[nt][r] + x[(size_t)m * 512 + n] + bo[n];
    }
}

extern "C" void kernel_launch(void* const* d_in, const int* in_sizes, int n_in,
                              void* d_out, int out_size, void* d_ws, size_t ws_size,
                              hipStream_t stream) {
  const float* x = (const float*)d_in[0];
  const float* pos = (const float*)d_in[1];
  const float* gamma = (const float*)d_in[2];
  const float* beta = (const float*)d_in[3];
  const float* wq = (const float*)d_in[4];
  const float* wk = (const float*)d_in[5];
  const float* wv = (const float*)d_in[6];
  const float* wpos = (const float*)d_in[7];
  const float* pbu = (const float*)d_in[8];
  const float* pbv = (const float*)d_in[9];
  const float* wo = (const float*)d_in[10];
  const float* bo = (const float*)d_in[11];
  float* out = (float*)d_out;
  char* ws = (char*)d_ws;

  unsigned short* y_bf = (unsigned short*)(ws + 0);
  unsigned short* pos_bf = (unsigned short*)(ws + 8388608);
  unsigned short* wt = (unsigned short*)(ws + 16777216);
  unsigned short* wo_t = (unsigned short*)(ws + 18874368);
  unsigned short* qb = (unsigned short*)(ws + 19398656);
  unsigned short* kb = (unsigned short*)(ws + 27787264);
  unsigned short* vb = (unsigned short*)(ws + 36175872);
  unsigned short* pb = (unsigned short*)(ws + 44564480);
  unsigned short* ctx = (unsigned short*)(ws + 52953088);
  unsigned short* bdraw = (unsigned short*)(ws + 61341696);

  prep_w<<<320, 256, 0, stream>>>(wq, wk, wv, wpos, wo, wt, wo_t);
  ln_pos_kernel<<<4096, 256, 0, stream>>>(x, pos, gamma, beta, y_bf, pos_bf);
  proj_gemm<<<dim3(128, 8, 4), 256, 0, stream>>>(y_bf, pos_bf, wt, qb, kb, vb, pb);

  size_t fixed = 61341696;
  size_t per = 2097152;  // one [T,T] bf16 per (b,h) pair
  int nch = 1;
  if (ws_size > fixed + per) nch = (int)((ws_size - fixed) / per);
  if (nch > 64) nch = 64;
  if (nch < 1) nch = 1;
  for (int bh0 = 0; bh0 < 64; bh0 += nch) {
    int c = (64 - bh0 < nch) ? (64 - bh0) : nch;
    bd_gemm<<<dim3(c, 16, 16), 256, 0, stream>>>(qb, pb, pbv, bdraw, bh0);
    attn_kernel<<<dim3(c, 16), 256, 0, stream>>>(qb, kb, vb, pbu, bdraw, ctx, bh0);
  }
  out_gemm<<<dim3(128, 8), 256, 0, stream>>>(ctx, wo_t, x, bo, out);
}

// Round 7
// 288.065 us; speedup vs baseline: 1.4129x; 1.4129x over previous
//
#include <hip/hip_runtime.h>
#include <math.h>

#define Bb 8
#define Tt 1024
#define Dd 512
#define Hh 8
#define HSs 64

typedef __attribute__((ext_vector_type(8))) short bf16x8;
typedef __attribute__((ext_vector_type(4))) float f32x4;
typedef __attribute__((ext_vector_type(8))) unsigned short u16x8;

__device__ __forceinline__ unsigned short f2bf(float f) {
  unsigned u = __float_as_uint(f);
  u += 0x7fffu + ((u >> 16) & 1u);
  return (unsigned short)(u >> 16);
}
__device__ __forceinline__ float bf2f(unsigned short s) {
  return __uint_as_float(((unsigned)s) << 16);
}
__device__ __forceinline__ void gload16(const void* g, void* l) {
  __builtin_amdgcn_global_load_lds(
      (const __attribute__((address_space(1))) void*)g,
      (__attribute__((address_space(3))) void*)l, 16, 0, 0);
}

// ---------------- prep: weights -> bf16, transposed, via LDS 64x64 tiles ----
__global__ __launch_bounds__(256) void prep_w(
    const float* __restrict__ wq, const float* __restrict__ wk,
    const float* __restrict__ wv, const float* __restrict__ wpos,
    const float* __restrict__ wo, unsigned short* __restrict__ wt,
    unsigned short* __restrict__ wo_t) {
  __shared__ unsigned short lds[64][65];
  int t = threadIdx.x, blk = blockIdx.x;
  if (blk < 256) {
    int z = blk >> 6, h = (blk >> 3) & 7, dt = blk & 7;
    const float* src = (z == 0) ? wq : (z == 1) ? wk : (z == 2) ? wv : wpos;
    const float* base = src + (size_t)h * 32768 + (size_t)dt * 4096;
#pragma unroll
    for (int p = 0; p < 4; ++p) {
      int idx = p * 1024 + t * 4;
      float4 v = *(const float4*)(base + idx);
      int d = idx >> 6, o = idx & 63;
      lds[o + 0][d] = f2bf(v.x);
      lds[o + 1][d] = f2bf(v.y);
      lds[o + 2][d] = f2bf(v.z);
      lds[o + 3][d] = f2bf(v.w);
    }
    __syncthreads();
    int o = t >> 2, dc = (t & 3) * 16;
    u16x8 w0, w1;
#pragma unroll
    for (int j = 0; j < 8; ++j) { w0[j] = lds[o][dc + j]; w1[j] = lds[o][dc + 8 + j]; }
    unsigned short* dst =
        wt + (size_t)z * 262144 + (size_t)((h << 6) + o) * 512 + dt * 64 + dc;
    *(u16x8*)dst = w0;
    *(u16x8*)(dst + 8) = w1;
  } else {
    int b2 = blk - 256, h = b2 >> 3, dt = b2 & 7;
    const float* base = wo + (size_t)h * 32768 + (size_t)dt * 64;
#pragma unroll
    for (int p = 0; p < 4; ++p) {
      int idx = p * 1024 + t * 4;
      int o = idx >> 6, dl = idx & 63;
      float4 v = *(const float4*)(base + (size_t)o * 512 + dl);
      lds[dl + 0][o] = f2bf(v.x);
      lds[dl + 1][o] = f2bf(v.y);
      lds[dl + 2][o] = f2bf(v.z);
      lds[dl + 3][o] = f2bf(v.w);
    }
    __syncthreads();
    int dl = t >> 2, oc = (t & 3) * 16;
    u16x8 w0, w1;
#pragma unroll
    for (int j = 0; j < 8; ++j) { w0[j] = lds[dl][oc + j]; w1[j] = lds[dl][oc + 8 + j]; }
    unsigned short* dst = wo_t + (size_t)(dt * 64 + dl) * 512 + (h << 6) + oc;
    *(u16x8*)dst = w0;
    *(u16x8*)(dst + 8) = w1;
  }
}

// ------------- LayerNorm (blocks 0..2047) + pos->bf16 (2048..4095) -------------
__global__ __launch_bounds__(256) void ln_pos_kernel(
    const float* __restrict__ x, const float* __restrict__ pos,
    const float* __restrict__ gamma, const float* __restrict__ beta,
    unsigned short* __restrict__ y, unsigned short* __restrict__ posb) {
  int wid = threadIdx.x >> 6, lane = threadIdx.x & 63;
  int blk = blockIdx.x;
  if (blk >= 2048) {
    int row = (blk - 2048) * 4 + wid;
    const float* pr = pos + (size_t)row * Dd + lane * 8;
    float4 a = *(const float4*)pr;
    float4 b = *(const float4*)(pr + 4);
    float v[8] = {a.x, a.y, a.z, a.w, b.x, b.y, b.z, b.w};
    u16x8 o8;
#pragma unroll
    for (int j = 0; j < 8; ++j) o8[j] = f2bf(v[j]);
    *(u16x8*)(posb + (size_t)row * Dd + lane * 8) = o8;
    return;
  }
  int row = blk * 4 + wid;
  const float* xr = x + (size_t)row * Dd + lane * 8;
  float4 v0 = *(const float4*)xr;
  float4 v1 = *(const float4*)(xr + 4);
  float xv[8] = {v0.x, v0.y, v0.z, v0.w, v1.x, v1.y, v1.z, v1.w};
  float s = 0.f, ss = 0.f;
#pragma unroll
  for (int j = 0; j < 8; ++j) { s += xv[j]; ss += xv[j] * xv[j]; }
#pragma unroll
  for (int m = 1; m < 64; m <<= 1) {
    s += __shfl_xor(s, m);
    ss += __shfl_xor(ss, m);
  }
  float mu = s * (1.f / 512.f);
  float var = ss * (1.f / 512.f) - mu * mu;
  float inv = rsqrtf(var + 1e-3f);
  const float4 g0 = *(const float4*)(gamma + lane * 8);
  const float4 g1 = *(const float4*)(gamma + lane * 8 + 4);
  const float4 b0 = *(const float4*)(beta + lane * 8);
  const float4 b1 = *(const float4*)(beta + lane * 8 + 4);
  float gv[8] = {g0.x, g0.y, g0.z, g0.w, g1.x, g1.y, g1.z, g1.w};
  float bv[8] = {b0.x, b0.y, b0.z, b0.w, b1.x, b1.y, b1.z, b1.w};
  u16x8 o8;
#pragma unroll
  for (int j = 0; j < 8; ++j)
    o8[j] = f2bf((xv[j] - mu) * inv * gv[j] + bv[j]);
  *(u16x8*)(y + (size_t)row * Dd + lane * 8) = o8;
}

// ------- projection GEMM: [8192,512] x B^T[512,512] -> q/k/v/p [B,H,T,64] -------
__global__ __launch_bounds__(256) void proj_gemm(
    const unsigned short* __restrict__ y, const unsigned short* __restrict__ posb,
    const unsigned short* __restrict__ wt, unsigned short* __restrict__ q,
    unsigned short* __restrict__ k, unsigned short* __restrict__ v,
    unsigned short* __restrict__ p) {
  __shared__ __align__(16) unsigned short la[2][64 * 32];
  __shared__ __align__(16) unsigned short lb[2][64 * 32];
  int z = blockIdx.z, h = blockIdx.y, m0 = blockIdx.x * 64;
  const unsigned short* A = (z < 3) ? y : posb;
  const unsigned short* Bt = wt + (size_t)z * 262144 + (size_t)h * 64 * 512;
  unsigned short* dst = (z == 0) ? q : (z == 1) ? k : (z == 2) ? v : p;
  int tid = threadIdx.x, wid = tid >> 6, lane = tid & 63;
  int g = lane >> 4, cl = lane & 15;
  int srow = (wid << 4) + (lane >> 2);
  int scsw = (((lane & 3) ^ ((lane >> 3) & 3)) << 3);
  const unsigned short* asrc = A + (size_t)(m0 + srow) * 512 + scsw;
  const unsigned short* bsrc = Bt + (size_t)srow * 512 + scsw;
  int rk = (cl >> 1) & 3;
  int aoff = (16 * wid + cl) * 32 + ((g ^ rk) << 3);
  f32x4 acc[4] = {};
  gload16(asrc, la[0] + (wid << 9));
  gload16(bsrc, lb[0] + (wid << 9));
  __syncthreads();
  for (int ks = 0; ks < 16; ++ks) {
    int cur = ks & 1;
    if (ks < 15) {
      gload16(asrc + (ks + 1) * 32, la[cur ^ 1] + (wid << 9));
      gload16(bsrc + (ks + 1) * 32, lb[cur ^ 1] + (wid << 9));
    }
    bf16x8 af = *(const bf16x8*)&la[cur][aoff];
#pragma unroll
    for (int nt = 0; nt < 4; ++nt) {
      bf16x8 bf = *(const bf16x8*)&lb[cur][(nt * 16 + cl) * 32 + ((g ^ rk) << 3)];
      acc[nt] = __builtin_amdgcn_mfma_f32_16x16x32_bf16(af, bf, acc[nt], 0, 0, 0);
    }
    __syncthreads();
  }
#pragma unroll
  for (int nt = 0; nt < 4; ++nt)
#pragma unroll
    for (int r = 0; r < 4; ++r) {
      int m = m0 + 16 * wid + g * 4 + r;
      int b = m >> 10, t = m & 1023;
      int o = nt * 16 + cl;
      dst[(((size_t)(b * 8 + h)) * 1024 + t) * 64 + o] = f2bf(acc[nt][r]);
    }
}

// ------- bd = rel-shifted (q + pos_bias_v).P^T per (b,h): [T,T] bf16 -------
// raw[r][c] -> shift[r][c+r-1023] if c >= 1023-r else shift[r-1][c+r+1]
// (r=0 low part dropped; shift[i][i+1] zeroed by bd_diag)
__global__ __launch_bounds__(256) void bd_gemm(
    const unsigned short* __restrict__ q, const unsigned short* __restrict__ p,
    const float* __restrict__ vbias, unsigned short* __restrict__ bdsh, int bh0) {
  __shared__ __align__(16) unsigned short pl[64 * 64];
  int px = blockIdx.x, bh = bh0 + px, b = bh >> 3, h = bh & 7;
  int r0 = blockIdx.y * 64, c0 = blockIdx.z * 64;
  int tid = threadIdx.x, wid = tid >> 6, lane = tid & 63;
  int g = lane >> 4, cl = lane & 15;
  const unsigned short* qbase =
      q + (((size_t)(b * 8 + h)) * 1024 + r0 + 16 * wid + cl) * 64;
  bf16x8 aq[2];
#pragma unroll
  for (int ks = 0; ks < 2; ++ks) {
    bf16x8 raw = *(const bf16x8*)&qbase[ks * 32 + g * 8];
#pragma unroll
    for (int j = 0; j < 8; ++j) {
      float f = bf2f((unsigned short)raw[j]) + vbias[h * 64 + ks * 32 + g * 8 + j];
      raw[j] = (short)f2bf(f);
    }
    aq[ks] = raw;
  }
  const unsigned short* pbase = p + (((size_t)(b * 8 + h)) * 1024 + c0) * 64;
  {
    int rlo = lane >> 3;
    int scc = ((lane & 7) ^ rlo) << 3;
#pragma unroll
    for (int it = 0; it < 2; ++it) {
      int seg = wid + it * 4;
      gload16(pbase + (size_t)(seg * 8 + rlo) * 64 + scc,
              (char*)pl + (seg << 10));
    }
  }
  __syncthreads();
  f32x4 acc[4] = {};
#pragma unroll
  for (int ks = 0; ks < 2; ++ks)
#pragma unroll
    for (int nt = 0; nt < 4; ++nt) {
      int row = nt * 16 + cl;
      int byte = row * 128 + ((ks * 64 + g * 16) ^ ((row & 7) << 4));
      bf16x8 bf = *(const bf16x8*)((char*)pl + byte);
      acc[nt] = __builtin_amdgcn_mfma_f32_16x16x32_bf16(aq[ks], bf, acc[nt], 0, 0, 0);
    }
  unsigned short* outb = bdsh + (size_t)px * 1048576;
#pragma unroll
  for (int nt = 0; nt < 4; ++nt)
#pragma unroll
    for (int r = 0; r < 4; ++r) {
      int rg = r0 + 16 * wid + g * 4 + r;
      int cg = c0 + nt * 16 + cl;
      bool hi = (cg >= 1023 - rg);
      int drow = hi ? rg : rg - 1;
      int dcol = hi ? (cg + rg - 1023) : (cg + rg + 1);
      if (drow >= 0)
        outb[(size_t)drow * 1024 + dcol] = f2bf(acc[nt][r]);
    }
}

// zero shift[i][i+1] for each pair slot
__global__ __launch_bounds__(1024) void bd_diag(unsigned short* __restrict__ bd) {
  int px = blockIdx.x, i = threadIdx.x;
  if (i < 1023)
    bd[(size_t)px * 1048576 + (size_t)i * 1024 + i + 1] = 0;
}

// ---------------- fused flash attention, shifted-bd staged in LDS ----------------
__global__ __launch_bounds__(256) void attn_kernel(
    const unsigned short* __restrict__ q, const unsigned short* __restrict__ kg,
    const unsigned short* __restrict__ vg, const float* __restrict__ ubias,
    const unsigned short* __restrict__ bdsh, unsigned short* __restrict__ ctx,
    int bh0) {
  __shared__ __align__(16) unsigned short kt[2][64 * 64];
  __shared__ __align__(16) unsigned short vt[2][64 * 64];
  __shared__ __align__(16) unsigned short bdt[2][64 * 64];
  __shared__ __align__(16) unsigned short pl[4][16 * 64];
  int px = blockIdx.x, bh = bh0 + px, b = bh >> 3, h = bh & 7;
  int i0 = blockIdx.y * 64;
  int tid = threadIdx.x, wid = tid >> 6, lane = tid & 63;
  int g = lane >> 4, cl = lane & 15;
  size_t bhoff = ((size_t)(b * 8 + h)) * 1024;
  const unsigned short* qbase = q + (bhoff + i0 + 16 * wid + cl) * 64;
  // Q + u-bias, pre-scaled by 0.125 (exact power-of-two, bf16-lossless)
  bf16x8 aq[2];
#pragma unroll
  for (int ks = 0; ks < 2; ++ks) {
    bf16x8 raw = *(const bf16x8*)&qbase[ks * 32 + g * 8];
#pragma unroll
    for (int j = 0; j < 8; ++j) {
      float f = (bf2f((unsigned short)raw[j]) + ubias[h * 64 + ks * 32 + g * 8 + j]) * 0.125f;
      raw[j] = (short)f2bf(f);
    }
    aq[ks] = raw;
  }
  f32x4 oacc[4] = {};
  float mrun[4], lrun[4];
#pragma unroll
  for (int r = 0; r < 4; ++r) { mrun[r] = -INFINITY; lrun[r] = 0.f; }
  const unsigned short* bdb = bdsh + (size_t)px * 1048576;
  const unsigned short* kbase = kg + bhoff * 64;
  const unsigned short* vbase = vg + bhoff * 64;
  int rlo = lane >> 3;                       // staging source row-in-8
  int scc = ((lane & 7) ^ rlo) << 3;         // pre-swizzled source chunk
  int kc0 = wid, kc1 = wid + 4;              // V staging: o = lane
  int vby0 = lane * 128 + ((kc0 * 16) ^ ((lane & 7) << 4));
  int vby1 = lane * 128 + ((kc1 * 16) ^ ((lane & 7) << 4));

  // prologue: stage tile 0 (K + BD via gload_lds, V via regs)
#pragma unroll
  for (int it = 0; it < 2; ++it) {
    int seg = wid + it * 4;
    gload16(kbase + (size_t)(seg * 8 + rlo) * 64 + scc, (char*)kt[0] + (seg << 10));
    gload16(bdb + (size_t)(i0 + seg * 8 + rlo) * 1024 + scc,
            (char*)bdt[0] + (seg << 10));
  }
  {
    u16x8 va, vb;
#pragma unroll
    for (int j = 0; j < 8; ++j) {
      va[j] = vbase[(size_t)(kc0 * 8 + j) * 64 + lane];
      vb[j] = vbase[(size_t)(kc1 * 8 + j) * 64 + lane];
    }
    *(u16x8*)((char*)vt[0] + vby0) = va;
    *(u16x8*)((char*)vt[0] + vby1) = vb;
  }
  __syncthreads();

  for (int jt = 0; jt < 16; ++jt) {
    int cur = jt & 1;
    unsigned short* ktc = kt[cur];
    unsigned short* vtc = vt[cur];
    unsigned short* bdtc = bdt[cur];
    u16x8 nva, nvb;
    if (jt < 15) {
      int j1 = (jt + 1) * 64;
#pragma unroll
      for (int it = 0; it < 2; ++it) {
        int seg = wid + it * 4;
        gload16(kbase + (size_t)(j1 + seg * 8 + rlo) * 64 + scc,
                (char*)kt[cur ^ 1] + (seg << 10));
        gload16(bdb + (size_t)(i0 + seg * 8 + rlo) * 1024 + j1 + scc,
                (char*)bdt[cur ^ 1] + (seg << 10));
      }
#pragma unroll
      for (int j = 0; j < 8; ++j) {
        nva[j] = vbase[(size_t)(j1 + kc0 * 8 + j) * 64 + lane];
        nvb[j] = vbase[(size_t)(j1 + kc1 * 8 + j) * 64 + lane];
      }
    }
    // S = Qu . K^T  (already scaled by 0.125 via aq)
    f32x4 sacc[4] = {};
#pragma unroll
    for (int ks = 0; ks < 2; ++ks)
#pragma unroll
      for (int nt = 0; nt < 4; ++nt) {
        int row = nt * 16 + cl;
        bf16x8 bk = *(const bf16x8*)((char*)ktc + row * 128 +
                                     ((ks * 64 + g * 16) ^ ((row & 7) << 4)));
        sacc[nt] = __builtin_amdgcn_mfma_f32_16x16x32_bf16(aq[ks], bk, sacc[nt], 0, 0, 0);
      }
    // add shifted bd from LDS (FMA with 0.125)
    float pmax[4];
#pragma unroll
    for (int r = 0; r < 4; ++r) pmax[r] = -INFINITY;
#pragma unroll
    for (int nt = 0; nt < 4; ++nt)
#pragma unroll
      for (int r = 0; r < 4; ++r) {
        int row = 16 * wid + g * 4 + r;
        int byte = row * 128 + (((nt * 16 + cl) * 2) ^ ((row & 7) << 4));
        float bdv = bf2f(*(const unsigned short*)((const char*)bdtc + byte));
        float s = fmaf(bdv, 0.125f, sacc[nt][r]);
        sacc[nt][r] = s;
        pmax[r] = fmaxf(pmax[r], s);
      }
#pragma unroll
    for (int r = 0; r < 4; ++r) {
      pmax[r] = fmaxf(pmax[r], __shfl_xor(pmax[r], 1));
      pmax[r] = fmaxf(pmax[r], __shfl_xor(pmax[r], 2));
      pmax[r] = fmaxf(pmax[r], __shfl_xor(pmax[r], 4));
      pmax[r] = fmaxf(pmax[r], __shfl_xor(pmax[r], 8));
    }
    float scl[4], rsum[4];
#pragma unroll
    for (int r = 0; r < 4; ++r) {
      float mn = fmaxf(mrun[r], pmax[r]);
      scl[r] = __expf(mrun[r] - mn);
      mrun[r] = mn;
      rsum[r] = 0.f;
    }
#pragma unroll
    for (int nt = 0; nt < 4; ++nt)
#pragma unroll
      for (int r = 0; r < 4; ++r) {
        float pv = __expf(sacc[nt][r] - mrun[r]);
        sacc[nt][r] = pv;
        rsum[r] += pv;
      }
#pragma unroll
    for (int r = 0; r < 4; ++r) {
      rsum[r] += __shfl_xor(rsum[r], 1);
      rsum[r] += __shfl_xor(rsum[r], 2);
      rsum[r] += __shfl_xor(rsum[r], 4);
      rsum[r] += __shfl_xor(rsum[r], 8);
      lrun[r] = lrun[r] * scl[r] + rsum[r];
    }
#pragma unroll
    for (int ot = 0; ot < 4; ++ot) {
      f32x4 t = oacc[ot];
#pragma unroll
      for (int r = 0; r < 4; ++r) t[r] *= scl[r];
      oacc[ot] = t;
    }
    // P -> LDS (wave-private), swizzled
    unsigned short* pw = &pl[wid][0];
#pragma unroll
    for (int nt = 0; nt < 4; ++nt)
#pragma unroll
      for (int r = 0; r < 4; ++r) {
        int row = g * 4 + r, col = nt * 16 + cl;
        *(unsigned short*)((char*)pw + row * 128 +
                           ((col * 2) ^ ((row & 7) << 4))) = f2bf(sacc[nt][r]);
      }
    bf16x8 ap[2];
#pragma unroll
    for (int ks = 0; ks < 2; ++ks)
      ap[ks] = *(const bf16x8*)((char*)pw + cl * 128 +
                                ((ks * 64 + g * 16) ^ ((cl & 7) << 4)));
    // O += P . V
#pragma unroll
    for (int ks = 0; ks < 2; ++ks)
#pragma unroll
      for (int ot = 0; ot < 4; ++ot) {
        int o = ot * 16 + cl;
        bf16x8 bv = *(const bf16x8*)((char*)vtc + o * 128 +
                                     ((ks * 64 + g * 16) ^ ((o & 7) << 4)));
        oacc[ot] = __builtin_amdgcn_mfma_f32_16x16x32_bf16(ap[ks], bv, oacc[ot], 0, 0, 0);
      }
    // late V write for next tile
    if (jt < 15) {
      unsigned short* vtn = vt[cur ^ 1];
      *(u16x8*)((char*)vtn + vby0) = nva;
      *(u16x8*)((char*)vtn + vby1) = nvb;
    }
    __syncthreads();
  }
  float rinv[4];
#pragma unroll
  for (int r = 0; r < 4; ++r) rinv[r] = __builtin_amdgcn_rcpf(lrun[r]);
#pragma unroll
  for (int ot = 0; ot < 4; ++ot)
#pragma unroll
    for (int r = 0; r < 4; ++r) {
      int i = i0 + 16 * wid + g * 4 + r;
      int c = h * 64 + ot * 16 + cl;
      ctx[((size_t)b * 1024 + i) * 512 + c] = f2bf(oacc[ot][r] * rinv[r]);
    }
}

// ---------------- output GEMM + bias + residual ----------------
__global__ __launch_bounds__(256) void out_gemm(
    const unsigned short* __restrict__ ctx, const unsigned short* __restrict__ wot,
    const float* __restrict__ x, const float* __restrict__ bo,
    float* __restrict__ out) {
  __shared__ __align__(16) unsigned short la[2][64 * 32];
  __shared__ __align__(16) unsigned short lb[2][64 * 32];
  int n0 = blockIdx.y * 64, m0 = blockIdx.x * 64;
  int tid = threadIdx.x, wid = tid >> 6, lane = tid & 63;
  int g = lane >> 4, cl = lane & 15;
  int srow = (wid << 4) + (lane >> 2);
  int scsw = (((lane & 3) ^ ((lane >> 3) & 3)) << 3);
  const unsigned short* asrc = ctx + (size_t)(m0 + srow) * 512 + scsw;
  const unsigned short* bsrc = wot + (size_t)(n0 + srow) * 512 + scsw;
  int rk = (cl >> 1) & 3;
  int aoff = (16 * wid + cl) * 32 + ((g ^ rk) << 3);
  f32x4 acc[4] = {};
  gload16(asrc, la[0] + (wid << 9));
  gload16(bsrc, lb[0] + (wid << 9));
  __syncthreads();
  for (int ks = 0; ks < 16; ++ks) {
    int cur = ks & 1;
    if (ks < 15) {
      gload16(asrc + (ks + 1) * 32, la[cur ^ 1] + (wid << 9));
      gload16(bsrc + (ks + 1) * 32, lb[cur ^ 1] + (wid << 9));
    }
    bf16x8 af = *(const bf16x8*)&la[cur][aoff];
#pragma unroll
    for (int nt = 0; nt < 4; ++nt) {
      bf16x8 bf = *(const bf16x8*)&lb[cur][(nt * 16 + cl) * 32 + ((g ^ rk) << 3)];
      acc[nt] = __builtin_amdgcn_mfma_f32_16x16x32_bf16(af, bf, acc[nt], 0, 0, 0);
    }
    __syncthreads();
  }
#pragma unroll
  for (int nt = 0; nt < 4; ++nt)
#pragma unroll
    for (int r = 0; r < 4; ++r) {
      int m = m0 + 16 * wid + g * 4 + r;
      int n = n0 + nt * 16 + cl;
      out[(size_t)m * 512 + n] = acc[nt][r] + x[(size_t)m * 512 + n] + bo[n];
    }
}

extern "C" void kernel_launch(void* const* d_in, const int* in_sizes, int n_in,
                              void* d_out, int out_size, void* d_ws, size_t ws_size,
                              hipStream_t stream) {
  const float* x = (const float*)d_in[0];
  const float* pos = (const float*)d_in[1];
  const float* gamma = (const float*)d_in[2];
  const float* beta = (const float*)d_in[3];
  const float* wq = (const float*)d_in[4];
  const float* wk = (const float*)d_in[5];
  const float* wv = (const float*)d_in[6];
  const float* wpos = (const float*)d_in[7];
  const float* pbu = (const float*)d_in[8];
  const float* pbv = (const float*)d_in[9];
  const float* wo = (const float*)d_in[10];
  const float* bo = (const float*)d_in[11];
  float* out = (float*)d_out;
  char* ws = (char*)d_ws;

  unsigned short* y_bf = (unsigned short*)(ws + 0);
  unsigned short* pos_bf = (unsigned short*)(ws + 8388608);
  unsigned short* wt = (unsigned short*)(ws + 16777216);
  unsigned short* wo_t = (unsigned short*)(ws + 18874368);
  unsigned short* qb = (unsigned short*)(ws + 19398656);
  unsigned short* kb = (unsigned short*)(ws + 27787264);
  unsigned short* vb = (unsigned short*)(ws + 36175872);
  unsigned short* pb = (unsigned short*)(ws + 44564480);
  unsigned short* ctx = (unsigned short*)(ws + 52953088);
  unsigned short* bdraw = (unsigned short*)(ws + 61341696);

  prep_w<<<320, 256, 0, stream>>>(wq, wk, wv, wpos, wo, wt, wo_t);
  ln_pos_kernel<<<4096, 256, 0, stream>>>(x, pos, gamma, beta, y_bf, pos_bf);
  proj_gemm<<<dim3(128, 8, 4), 256, 0, stream>>>(y_bf, pos_bf, wt, qb, kb, vb, pb);

  size_t fixed = 61341696;
  size_t per = 2097152;  // one [T,T] bf16 per (b,h) pair
  int nch = 1;
  if (ws_size > fixed + per) nch = (int)((ws_size - fixed) / per);
  if (nch > 64) nch = 64;
  if (nch < 1) nch = 1;
  bd_diag<<<dim3(nch), 1024, 0, stream>>>(bdraw);
  for (int bh0 = 0; bh0 < 64; bh0 += nch) {
    int c = (64 - bh0 < nch) ? (64 - bh0) : nch;
    bd_gemm<<<dim3(c, 16, 16), 256, 0, stream>>>(qb, pb, pbv, bdraw, bh0);
    attn_kernel<<<dim3(c, 16), 256, 0, stream>>>(qb, kb, vb, pbu, bdraw, ctx, bh0);
  }
  out_gemm<<<dim3(128, 8), 256, 0, stream>>>(ctx, wo_t, x, bo, out);
}

// Round 9
// 282.506 us; speedup vs baseline: 1.4407x; 1.0197x over previous
//
#include <hip/hip_runtime.h>
#include <math.h>

#define Bb 8
#define Tt 1024
#define Dd 512
#define Hh 8
#define HSs 64

typedef __attribute__((ext_vector_type(8))) short bf16x8;
typedef __attribute__((ext_vector_type(4))) float f32x4;
typedef __attribute__((ext_vector_type(8))) unsigned short u16x8;

__device__ __forceinline__ unsigned short f2bf(float f) {
  unsigned u = __float_as_uint(f);
  u += 0x7fffu + ((u >> 16) & 1u);
  return (unsigned short)(u >> 16);
}
__device__ __forceinline__ float bf2f(unsigned short s) {
  return __uint_as_float(((unsigned)s) << 16);
}
__device__ __forceinline__ void gload16(const void* g, void* l) {
  __builtin_amdgcn_global_load_lds(
      (const __attribute__((address_space(1))) void*)g,
      (__attribute__((address_space(3))) void*)l, 16, 0, 0);
}

// ---------------- prep: weights -> bf16, transposed, via LDS 64x64 tiles ----
__global__ __launch_bounds__(256) void prep_w(
    const float* __restrict__ wq, const float* __restrict__ wk,
    const float* __restrict__ wv, const float* __restrict__ wpos,
    const float* __restrict__ wo, unsigned short* __restrict__ wt,
    unsigned short* __restrict__ wo_t) {
  __shared__ unsigned short lds[64][65];
  int t = threadIdx.x, blk = blockIdx.x;
  if (blk < 256) {
    int z = blk >> 6, h = (blk >> 3) & 7, dt = blk & 7;
    const float* src = (z == 0) ? wq : (z == 1) ? wk : (z == 2) ? wv : wpos;
    const float* base = src + (size_t)h * 32768 + (size_t)dt * 4096;
#pragma unroll
    for (int p = 0; p < 4; ++p) {
      int idx = p * 1024 + t * 4;
      float4 v = *(const float4*)(base + idx);
      int d = idx >> 6, o = idx & 63;
      lds[o + 0][d] = f2bf(v.x);
      lds[o + 1][d] = f2bf(v.y);
      lds[o + 2][d] = f2bf(v.z);
      lds[o + 3][d] = f2bf(v.w);
    }
    __syncthreads();
    int o = t >> 2, dc = (t & 3) * 16;
    u16x8 w0, w1;
#pragma unroll
    for (int j = 0; j < 8; ++j) { w0[j] = lds[o][dc + j]; w1[j] = lds[o][dc + 8 + j]; }
    unsigned short* dst =
        wt + (size_t)z * 262144 + (size_t)((h << 6) + o) * 512 + dt * 64 + dc;
    *(u16x8*)dst = w0;
    *(u16x8*)(dst + 8) = w1;
  } else {
    int b2 = blk - 256, h = b2 >> 3, dt = b2 & 7;
    const float* base = wo + (size_t)h * 32768 + (size_t)dt * 64;
#pragma unroll
    for (int p = 0; p < 4; ++p) {
      int idx = p * 1024 + t * 4;
      int o = idx >> 6, dl = idx & 63;
      float4 v = *(const float4*)(base + (size_t)o * 512 + dl);
      lds[dl + 0][o] = f2bf(v.x);
      lds[dl + 1][o] = f2bf(v.y);
      lds[dl + 2][o] = f2bf(v.z);
      lds[dl + 3][o] = f2bf(v.w);
    }
    __syncthreads();
    int dl = t >> 2, oc = (t & 3) * 16;
    u16x8 w0, w1;
#pragma unroll
    for (int j = 0; j < 8; ++j) { w0[j] = lds[dl][oc + j]; w1[j] = lds[dl][oc + 8 + j]; }
    unsigned short* dst = wo_t + (size_t)(dt * 64 + dl) * 512 + (h << 6) + oc;
    *(u16x8*)dst = w0;
    *(u16x8*)(dst + 8) = w1;
  }
}

// ------------- LayerNorm (blocks 0..2047) + pos->bf16 (2048..4095) -------------
__global__ __launch_bounds__(256) void ln_pos_kernel(
    const float* __restrict__ x, const float* __restrict__ pos,
    const float* __restrict__ gamma, const float* __restrict__ beta,
    unsigned short* __restrict__ y, unsigned short* __restrict__ posb) {
  int wid = threadIdx.x >> 6, lane = threadIdx.x & 63;
  int blk = blockIdx.x;
  if (blk >= 2048) {
    int row = (blk - 2048) * 4 + wid;
    const float* pr = pos + (size_t)row * Dd + lane * 8;
    float4 a = *(const float4*)pr;
    float4 b = *(const float4*)(pr + 4);
    float v[8] = {a.x, a.y, a.z, a.w, b.x, b.y, b.z, b.w};
    u16x8 o8;
#pragma unroll
    for (int j = 0; j < 8; ++j) o8[j] = f2bf(v[j]);
    *(u16x8*)(posb + (size_t)row * Dd + lane * 8) = o8;
    return;
  }
  int row = blk * 4 + wid;
  const float* xr = x + (size_t)row * Dd + lane * 8;
  float4 v0 = *(const float4*)xr;
  float4 v1 = *(const float4*)(xr + 4);
  float xv[8] = {v0.x, v0.y, v0.z, v0.w, v1.x, v1.y, v1.z, v1.w};
  float s = 0.f, ss = 0.f;
#pragma unroll
  for (int j = 0; j < 8; ++j) { s += xv[j]; ss += xv[j] * xv[j]; }
#pragma unroll
  for (int m = 1; m < 64; m <<= 1) {
    s += __shfl_xor(s, m);
    ss += __shfl_xor(ss, m);
  }
  float mu = s * (1.f / 512.f);
  float var = ss * (1.f / 512.f) - mu * mu;
  float inv = rsqrtf(var + 1e-3f);
  const float4 g0 = *(const float4*)(gamma + lane * 8);
  const float4 g1 = *(const float4*)(gamma + lane * 8 + 4);
  const float4 b0 = *(const float4*)(beta + lane * 8);
  const float4 b1 = *(const float4*)(beta + lane * 8 + 4);
  float gv[8] = {g0.x, g0.y, g0.z, g0.w, g1.x, g1.y, g1.z, g1.w};
  float bv[8] = {b0.x, b0.y, b0.z, b0.w, b1.x, b1.y, b1.z, b1.w};
  u16x8 o8;
#pragma unroll
  for (int j = 0; j < 8; ++j)
    o8[j] = f2bf((xv[j] - mu) * inv * gv[j] + bv[j]);
  *(u16x8*)(y + (size_t)row * Dd + lane * 8) = o8;
}

// ------- projection GEMM: [8192,512] x B^T[512,512] -> q/k/v/p [B,H,T,64] -------
__global__ __launch_bounds__(256) void proj_gemm(
    const unsigned short* __restrict__ y, const unsigned short* __restrict__ posb,
    const unsigned short* __restrict__ wt, unsigned short* __restrict__ q,
    unsigned short* __restrict__ k, unsigned short* __restrict__ v,
    unsigned short* __restrict__ p) {
  __shared__ __align__(16) unsigned short la[2][64 * 32];
  __shared__ __align__(16) unsigned short lb[2][64 * 32];
  int z = blockIdx.z, h = blockIdx.y, m0 = blockIdx.x * 64;
  const unsigned short* A = (z < 3) ? y : posb;
  const unsigned short* Bt = wt + (size_t)z * 262144 + (size_t)h * 64 * 512;
  unsigned short* dst = (z == 0) ? q : (z == 1) ? k : (z == 2) ? v : p;
  int tid = threadIdx.x, wid = tid >> 6, lane = tid & 63;
  int g = lane >> 4, cl = lane & 15;
  int srow = (wid << 4) + (lane >> 2);
  int scsw = (((lane & 3) ^ ((lane >> 3) & 3)) << 3);
  const unsigned short* asrc = A + (size_t)(m0 + srow) * 512 + scsw;
  const unsigned short* bsrc = Bt + (size_t)srow * 512 + scsw;
  int rk = (cl >> 1) & 3;
  int aoff = (16 * wid + cl) * 32 + ((g ^ rk) << 3);
  f32x4 acc[4] = {};
  gload16(asrc, la[0] + (wid << 9));
  gload16(bsrc, lb[0] + (wid << 9));
  __syncthreads();
  for (int ks = 0; ks < 16; ++ks) {
    int cur = ks & 1;
    if (ks < 15) {
      gload16(asrc + (ks + 1) * 32, la[cur ^ 1] + (wid << 9));
      gload16(bsrc + (ks + 1) * 32, lb[cur ^ 1] + (wid << 9));
    }
    bf16x8 af = *(const bf16x8*)&la[cur][aoff];
#pragma unroll
    for (int nt = 0; nt < 4; ++nt) {
      bf16x8 bf = *(const bf16x8*)&lb[cur][(nt * 16 + cl) * 32 + ((g ^ rk) << 3)];
      acc[nt] = __builtin_amdgcn_mfma_f32_16x16x32_bf16(af, bf, acc[nt], 0, 0, 0);
    }
    __syncthreads();
  }
#pragma unroll
  for (int nt = 0; nt < 4; ++nt)
#pragma unroll
    for (int r = 0; r < 4; ++r) {
      int m = m0 + 16 * wid + g * 4 + r;
      int b = m >> 10, t = m & 1023;
      int o = nt * 16 + cl;
      dst[(((size_t)(b * 8 + h)) * 1024 + t) * 64 + o] = f2bf(acc[nt][r]);
    }
}

// ------- V transpose: [B,H,T,64] -> [B,H,64,T], coalesced via LDS tile -------
__global__ __launch_bounds__(256) void v_transpose(
    const unsigned short* __restrict__ vb, unsigned short* __restrict__ vtr) {
  __shared__ unsigned short lds[64][65];
  int blk = blockIdx.x;                  // 1024: bh*16 + tcol
  int bh = blk >> 4, t0 = (blk & 15) * 64;
  int tid = threadIdx.x;
  const unsigned short* src = vb + ((size_t)bh * 1024 + t0) * 64;
#pragma unroll
  for (int it = 0; it < 2; ++it) {
    int row = (tid >> 3) + it * 32, oc = (tid & 7) * 8;
    u16x8 v = *(const u16x8*)&src[(size_t)row * 64 + oc];
#pragma unroll
    for (int j = 0; j < 8; ++j) lds[row][oc + j] = v[j];
  }
  __syncthreads();
  int o = tid >> 2, tc = (tid & 3) * 16;
  u16x8 w0, w1;
#pragma unroll
  for (int j = 0; j < 8; ++j) { w0[j] = lds[tc + j][o]; w1[j] = lds[tc + 8 + j][o]; }
  unsigned short* dst = vtr + ((size_t)bh * 64 + o) * 1024 + t0 + tc;
  *(u16x8*)dst = w0;
  *(u16x8*)(dst + 8) = w1;
}

// ------- bd = rel-shifted (q + pos_bias_v).P^T per (b,h): [T,T] bf16 -------
// raw[r][c] -> shift[r][c+r-1023] if c >= 1023-r else shift[r-1][c+r+1]
__global__ __launch_bounds__(256) void bd_gemm(
    const unsigned short* __restrict__ q, const unsigned short* __restrict__ p,
    const float* __restrict__ vbias, unsigned short* __restrict__ bdsh, int bh0) {
  __shared__ __align__(16) unsigned short pl[64 * 64];
  int px = blockIdx.x, bh = bh0 + px, b = bh >> 3, h = bh & 7;
  int r0 = blockIdx.y * 64, c0 = blockIdx.z * 64;
  int tid = threadIdx.x, wid = tid >> 6, lane = tid & 63;
  int g = lane >> 4, cl = lane & 15;
  const unsigned short* qbase =
      q + (((size_t)(b * 8 + h)) * 1024 + r0 + 16 * wid + cl) * 64;
  bf16x8 aq[2];
#pragma unroll
  for (int ks = 0; ks < 2; ++ks) {
    bf16x8 raw = *(const bf16x8*)&qbase[ks * 32 + g * 8];
#pragma unroll
    for (int j = 0; j < 8; ++j) {
      float f = bf2f((unsigned short)raw[j]) + vbias[h * 64 + ks * 32 + g * 8 + j];
      raw[j] = (short)f2bf(f);
    }
    aq[ks] = raw;
  }
  const unsigned short* pbase = p + (((size_t)(b * 8 + h)) * 1024 + c0) * 64;
  {
    int rlo = lane >> 3;
    int scc = ((lane & 7) ^ rlo) << 3;
#pragma unroll
    for (int it = 0; it < 2; ++it) {
      int seg = wid + it * 4;
      gload16(pbase + (size_t)(seg * 8 + rlo) * 64 + scc,
              (char*)pl + (seg << 10));
    }
  }
  __syncthreads();
  f32x4 acc[4] = {};
#pragma unroll
  for (int ks = 0; ks < 2; ++ks)
#pragma unroll
    for (int nt = 0; nt < 4; ++nt) {
      int row = nt * 16 + cl;
      int byte = row * 128 + ((ks * 64 + g * 16) ^ ((row & 7) << 4));
      bf16x8 bf = *(const bf16x8*)((char*)pl + byte);
      acc[nt] = __builtin_amdgcn_mfma_f32_16x16x32_bf16(aq[ks], bf, acc[nt], 0, 0, 0);
    }
  unsigned short* outb = bdsh + (size_t)px * 1048576;
#pragma unroll
  for (int nt = 0; nt < 4; ++nt)
#pragma unroll
    for (int r = 0; r < 4; ++r) {
      int rg = r0 + 16 * wid + g * 4 + r;
      int cg = c0 + nt * 16 + cl;
      bool hi = (cg >= 1023 - rg);
      int drow = hi ? rg : rg - 1;
      int dcol = hi ? (cg + rg - 1023) : (cg + rg + 1);
      if (drow >= 0)
        outb[(size_t)drow * 1024 + dcol] = f2bf(acc[nt][r]);
    }
}

// zero shift[i][i+1] for each pair slot
__global__ __launch_bounds__(1024) void bd_diag(unsigned short* __restrict__ bd) {
  int px = blockIdx.x, i = threadIdx.x;
  if (i < 1023)
    bd[(size_t)px * 1048576 + (size_t)i * 1024 + i + 1] = 0;
}

// ------- fused flash attention: 8 waves / 128 Q-rows, all tiles via gload_lds ----
#define SCEXP 0.18033688f  /* 0.125 * log2(e): softmax done base-2 */
__global__ __launch_bounds__(512) void attn_kernel(
    const unsigned short* __restrict__ q, const unsigned short* __restrict__ kg,
    const unsigned short* __restrict__ vtr, const float* __restrict__ ubias,
    const unsigned short* __restrict__ bdsh, unsigned short* __restrict__ ctx,
    int bh0) {
  __shared__ __align__(16) unsigned short kt[2][64 * 64];    // K rows [j][d]
  __shared__ __align__(16) unsigned short vt[2][64 * 64];    // V^T rows [o][j]
  __shared__ __align__(16) unsigned short bdt[2][128 * 64];  // bd [i][j]
  __shared__ __align__(16) unsigned short pl[8][16 * 64];
  int px = blockIdx.x, bh = bh0 + px, b = bh >> 3, h = bh & 7;
  int i0 = blockIdx.y * 128;
  int tid = threadIdx.x, wid = tid >> 6, lane = tid & 63;
  int g = lane >> 4, cl = lane & 15;
  size_t bhoff = (size_t)bh * 1024;
  const unsigned short* qbase = q + (bhoff + i0 + 16 * wid + cl) * 64;
  // Q + u-bias, pre-scaled by 0.125*log2e
  bf16x8 aq[2];
#pragma unroll
  for (int ks = 0; ks < 2; ++ks) {
    bf16x8 raw = *(const bf16x8*)&qbase[ks * 32 + g * 8];
#pragma unroll
    for (int j = 0; j < 8; ++j) {
      float f = (bf2f((unsigned short)raw[j]) + ubias[h * 64 + ks * 32 + g * 8 + j]) * SCEXP;
      raw[j] = (short)f2bf(f);
    }
    aq[ks] = raw;
  }
  f32x4 oacc[4] = {};
  float mrun[4], lrun[4];
#pragma unroll
  for (int r = 0; r < 4; ++r) { mrun[r] = -INFINITY; lrun[r] = 0.f; }
  const unsigned short* bdb = bdsh + (size_t)px * 1048576;
  const unsigned short* kbase = kg + bhoff * 64;
  const unsigned short* vtb = vtr + (size_t)bh * 65536;
  int rlo = lane >> 3;                       // staging row-in-seg
  int scc = ((lane & 7) ^ rlo) << 3;         // pre-swizzled source chunk

  // prologue: stage tile 0 (K, V^T: 1 call each; bd: 2 calls)
  gload16(kbase + (size_t)(wid * 8 + rlo) * 64 + scc, (char*)kt[0] + (wid << 10));
  gload16(vtb + (size_t)(wid * 8 + rlo) * 1024 + scc, (char*)vt[0] + (wid << 10));
#pragma unroll
  for (int it = 0; it < 2; ++it) {
    int seg = wid + it * 8;
    gload16(bdb + (size_t)(i0 + seg * 8 + rlo) * 1024 + scc,
            (char*)bdt[0] + (seg << 10));
  }
  __syncthreads();

  for (int jt = 0; jt < 16; ++jt) {
    int cur = jt & 1;
    unsigned short* ktc = kt[cur];
    unsigned short* vtc = vt[cur];
    unsigned short* bdtc = bdt[cur];
    if (jt < 15) {
      int j1 = (jt + 1) * 64;
      gload16(kbase + (size_t)(j1 + wid * 8 + rlo) * 64 + scc,
              (char*)kt[cur ^ 1] + (wid << 10));
      gload16(vtb + (size_t)(wid * 8 + rlo) * 1024 + j1 + scc,
              (char*)vt[cur ^ 1] + (wid << 10));
#pragma unroll
      for (int it = 0; it < 2; ++it) {
        int seg = wid + it * 8;
        gload16(bdb + (size_t)(i0 + seg * 8 + rlo) * 1024 + j1 + scc,
                (char*)bdt[cur ^ 1] + (seg << 10));
      }
    }
    // S = Qu . K^T  (scaled by 0.125*log2e via aq)
    f32x4 sacc[4] = {};
#pragma unroll
    for (int ks = 0; ks < 2; ++ks)
#pragma unroll
      for (int nt = 0; nt < 4; ++nt) {
        int row = nt * 16 + cl;
        bf16x8 bk = *(const bf16x8*)((char*)ktc + row * 128 +
                                     ((ks * 64 + g * 16) ^ ((row & 7) << 4)));
        sacc[nt] = __builtin_amdgcn_mfma_f32_16x16x32_bf16(aq[ks], bk, sacc[nt], 0, 0, 0);
      }
    // add shifted bd from LDS (FMA with SCEXP)
    float pmax[4];
#pragma unroll
    for (int r = 0; r < 4; ++r) pmax[r] = -INFINITY;
#pragma unroll
    for (int nt = 0; nt < 4; ++nt)
#pragma unroll
      for (int r = 0; r < 4; ++r) {
        int row = 16 * wid + g * 4 + r;
        int byte = row * 128 + (((nt * 16 + cl) * 2) ^ ((row & 7) << 4));
        float bdv = bf2f(*(const unsigned short*)((const char*)bdtc + byte));
        float s = fmaf(bdv, SCEXP, sacc[nt][r]);
        sacc[nt][r] = s;
        pmax[r] = fmaxf(pmax[r], s);
      }
#pragma unroll
    for (int r = 0; r < 4; ++r) {
      pmax[r] = fmaxf(pmax[r], __shfl_xor(pmax[r], 1));
      pmax[r] = fmaxf(pmax[r], __shfl_xor(pmax[r], 2));
      pmax[r] = fmaxf(pmax[r], __shfl_xor(pmax[r], 4));
      pmax[r] = fmaxf(pmax[r], __shfl_xor(pmax[r], 8));
    }
    float scl[4], rsum[4];
#pragma unroll
    for (int r = 0; r < 4; ++r) {
      float mn = fmaxf(mrun[r], pmax[r]);
      scl[r] = __builtin_exp2f(mrun[r] - mn);
      mrun[r] = mn;
      rsum[r] = 0.f;
    }
#pragma unroll
    for (int nt = 0; nt < 4; ++nt)
#pragma unroll
      for (int r = 0; r < 4; ++r) {
        float pv = __builtin_exp2f(sacc[nt][r] - mrun[r]);
        sacc[nt][r] = pv;
        rsum[r] += pv;
      }
#pragma unroll
    for (int r = 0; r < 4; ++r) {
      rsum[r] += __shfl_xor(rsum[r], 1);
      rsum[r] += __shfl_xor(rsum[r], 2);
      rsum[r] += __shfl_xor(rsum[r], 4);
      rsum[r] += __shfl_xor(rsum[r], 8);
      lrun[r] = lrun[r] * scl[r] + rsum[r];
    }
#pragma unroll
    for (int ot = 0; ot < 4; ++ot) {
      f32x4 t = oacc[ot];
#pragma unroll
      for (int r = 0; r < 4; ++r) t[r] *= scl[r];
      oacc[ot] = t;
    }
    // P -> LDS (wave-private), swizzled
    unsigned short* pw = &pl[wid][0];
#pragma unroll
    for (int nt = 0; nt < 4; ++nt)
#pragma unroll
      for (int r = 0; r < 4; ++r) {
        int row = g * 4 + r, col = nt * 16 + cl;
        *(unsigned short*)((char*)pw + row * 128 +
                           ((col * 2) ^ ((row & 7) << 4))) = f2bf(sacc[nt][r]);
      }
    bf16x8 ap[2];
#pragma unroll
    for (int ks = 0; ks < 2; ++ks)
      ap[ks] = *(const bf16x8*)((char*)pw + cl * 128 +
                                ((ks * 64 + g * 16) ^ ((cl & 7) << 4)));
    // O += P . V
#pragma unroll
    for (int ks = 0; ks < 2; ++ks)
#pragma unroll
      for (int ot = 0; ot < 4; ++ot) {
        int o = ot * 16 + cl;
        bf16x8 bv = *(const bf16x8*)((char*)vtc + o * 128 +
                                     ((ks * 64 + g * 16) ^ ((o & 7) << 4)));
        oacc[ot] = __builtin_amdgcn_mfma_f32_16x16x32_bf16(ap[ks], bv, oacc[ot], 0, 0, 0);
      }
    __syncthreads();
  }
  float rinv[4];
#pragma unroll
  for (int r = 0; r < 4; ++r) rinv[r] = __builtin_amdgcn_rcpf(lrun[r]);
#pragma unroll
  for (int ot = 0; ot < 4; ++ot)
#pragma unroll
    for (int r = 0; r < 4; ++r) {
      int i = i0 + 16 * wid + g * 4 + r;
      int c = h * 64 + ot * 16 + cl;
      ctx[((size_t)b * 1024 + i) * 512 + c] = f2bf(oacc[ot][r] * rinv[r]);
    }
}

// ---------------- output GEMM + bias + residual ----------------
__global__ __launch_bounds__(256) void out_gemm(
    const unsigned short* __restrict__ ctx, const unsigned short* __restrict__ wot,
    const float* __restrict__ x, const float* __restrict__ bo,
    float* __restrict__ out) {
  __shared__ __align__(16) unsigned short la[2][64 * 32];
  __shared__ __align__(16) unsigned short lb[2][64 * 32];
  int n0 = blockIdx.y * 64, m0 = blockIdx.x * 64;
  int tid = threadIdx.x, wid = tid >> 6, lane = tid & 63;
  int g = lane >> 4, cl = lane & 15;
  int srow = (wid << 4) + (lane >> 2);
  int scsw = (((lane & 3) ^ ((lane >> 3) & 3)) << 3);
  const unsigned short* asrc = ctx + (size_t)(m0 + srow) * 512 + scsw;
  const unsigned short* bsrc = wot + (size_t)(n0 + srow) * 512 + scsw;
  int rk = (cl >> 1) & 3;
  int aoff = (16 * wid + cl) * 32 + ((g ^ rk) << 3);
  f32x4 acc[4] = {};
  gload16(asrc, la[0] + (wid << 9));
  gload16(bsrc, lb[0] + (wid << 9));
  __syncthreads();
  for (int ks = 0; ks < 16; ++ks) {
    int cur = ks & 1;
    if (ks < 15) {
      gload16(asrc + (ks + 1) * 32, la[cur ^ 1] + (wid << 9));
      gload16(bsrc + (ks + 1) * 32, lb[cur ^ 1] + (wid << 9));
    }
    bf16x8 af = *(const bf16x8*)&la[cur][aoff];
#pragma unroll
    for (int nt = 0; nt < 4; ++nt) {
      bf16x8 bf = *(const bf16x8*)&lb[cur][(nt * 16 + cl) * 32 + ((g ^ rk) << 3)];
      acc[nt] = __builtin_amdgcn_mfma_f32_16x16x32_bf16(af, bf, acc[nt], 0, 0, 0);
    }
    __syncthreads();
  }
#pragma unroll
  for (int nt = 0; nt < 4; ++nt)
#pragma unroll
    for (int r = 0; r < 4; ++r) {
      int m = m0 + 16 * wid + g * 4 + r;
      int n = n0 + nt * 16 + cl;
      out[(size_t)m * 512 + n] = acc[nt][r] + x[(size_t)m * 512 + n] + bo[n];
    }
}

extern "C" void kernel_launch(void* const* d_in, const int* in_sizes, int n_in,
                              void* d_out, int out_size, void* d_ws, size_t ws_size,
                              hipStream_t stream) {
  const float* x = (const float*)d_in[0];
  const float* pos = (const float*)d_in[1];
  const float* gamma = (const float*)d_in[2];
  const float* beta = (const float*)d_in[3];
  const float* wq = (const float*)d_in[4];
  const float* wk = (const float*)d_in[5];
  const float* wv = (const float*)d_in[6];
  const float* wpos = (const float*)d_in[7];
  const float* pbu = (const float*)d_in[8];
  const float* pbv = (const float*)d_in[9];
  const float* wo = (const float*)d_in[10];
  const float* bo = (const float*)d_in[11];
  float* out = (float*)d_out;
  char* ws = (char*)d_ws;

  unsigned short* y_bf = (unsigned short*)(ws + 0);
  unsigned short* pos_bf = (unsigned short*)(ws + 8388608);
  unsigned short* wt = (unsigned short*)(ws + 16777216);
  unsigned short* wo_t = (unsigned short*)(ws + 18874368);
  unsigned short* qb = (unsigned short*)(ws + 19398656);
  unsigned short* kb = (unsigned short*)(ws + 27787264);
  unsigned short* vb = (unsigned short*)(ws + 36175872);
  unsigned short* pb = (unsigned short*)(ws + 44564480);
  unsigned short* ctx = (unsigned short*)(ws + 52953088);
  unsigned short* vtrans = (unsigned short*)(ws + 61341696);
  unsigned short* bdraw = (unsigned short*)(ws + 69730304);

  prep_w<<<320, 256, 0, stream>>>(wq, wk, wv, wpos, wo, wt, wo_t);
  ln_pos_kernel<<<4096, 256, 0, stream>>>(x, pos, gamma, beta, y_bf, pos_bf);
  proj_gemm<<<dim3(128, 8, 4), 256, 0, stream>>>(y_bf, pos_bf, wt, qb, kb, vb, pb);
  v_transpose<<<1024, 256, 0, stream>>>(vb, vtrans);

  size_t fixed = 69730304;
  size_t per = 2097152;  // one [T,T] bf16 per (b,h) pair
  int nch = 1;
  if (ws_size > fixed + per) nch = (int)((ws_size - fixed) / per);
  if (nch > 64) nch = 64;
  if (nch < 1) nch = 1;
  bd_diag<<<dim3(nch), 1024, 0, stream>>>(bdraw);
  for (int bh0 = 0; bh0 < 64; bh0 += nch) {
    int c = (64 - bh0 < nch) ? (64 - bh0) : nch;
    bd_gemm<<<dim3(c, 16, 16), 256, 0, stream>>>(qb, pb, pbv, bdraw, bh0);
    attn_kernel<<<dim3(c, 8), 512, 0, stream>>>(qb, kb, vtrans, pbu, bdraw, ctx, bh0);
  }
  out_gemm<<<dim3(128, 8), 256, 0, stream>>>(ctx, wo_t, x, bo, out);
}